// Round 6
// baseline (382.029 us; speedup 1.0000x reference)
//
#include <hip/hip_runtime.h>

// Problem constants (match reference setup_inputs)
#define N_NODES 500000
#define MEM_D   128
#define MSG_W   257          // MSG_D + 1
#define BATCH   200000

// Fused work-index space (units = float4 slots)
#define G_UNITS   6400000    // BATCH * 32       (gather mem_out)
#define M_UNITS   16000000   // N_NODES * 32     (new_memory)
#define S_UNITS   32125000   // (N_NODES/4)*257  (new_messages)
#define GM_UNITS  22400000   // G_UNITS + M_UNITS
#define TOTAL_UNITS 54525000 // G + M + S

typedef float f4 __attribute__((ext_vector_type(4)));

__device__ __forceinline__ f4 nt_load4(const f4* p) {
    return __builtin_nontemporal_load(p);    // read-once streams: don't pollute L2
}

// ---------------------------------------------------------------------------
// Pass 1: last-wins winner map + touched flag.
// winner and flag are both pre-initialized to 0xFF by ONE memset:
//   winner[n] == -1   -> node not written        (atomicMax with i keeps max i)
//   flag[n]   == 0xFF -> keep old message row;  scatter writes 0 = store new
__global__ void scatter_idx_kernel(const int* __restrict__ node_idxs,
                                   const int* __restrict__ nodes,
                                   int* __restrict__ winner,
                                   unsigned char* __restrict__ flag) {
    int i = blockIdx.x * blockDim.x + threadIdx.x;
    int stride = gridDim.x * blockDim.x;
    for (; i < BATCH; i += stride) {
        atomicMax(&winner[node_idxs[i]], i);   // last occurrence wins
        flag[nodes[i]] = 0;                    // idempotent, race OK
    }
}

// ---------------------------------------------------------------------------
// Pass 2 (fused, flat grid-stride over all three regions — proven best
// structure r3). Stores are PLAIN (through L2) this round; nt only on
// pure-streaming loads.
__global__ void fused_kernel(const float* __restrict__ memory,
                             const float* __restrict__ last_update,
                             const float* __restrict__ messages,
                             const float* __restrict__ nid2msg,
                             const float* __restrict__ values,
                             const int* __restrict__ node_idxs,
                             const int* __restrict__ winner,
                             const unsigned char* __restrict__ flag,
                             float* __restrict__ mem_out,
                             float* __restrict__ lu_out,
                             float* __restrict__ new_memory,
                             float* __restrict__ new_messages) {
    const f4* mem4 = reinterpret_cast<const f4*>(memory);
    const f4* val4 = reinterpret_cast<const f4*>(values);
    const f4* msg4 = reinterpret_cast<const f4*>(messages);
    const f4* src4 = reinterpret_cast<const f4*>(nid2msg);
    f4* memout4 = reinterpret_cast<f4*>(mem_out);
    f4* newmem4 = reinterpret_cast<f4*>(new_memory);
    f4* newmsg4 = reinterpret_cast<f4*>(new_messages);

    int i = blockIdx.x * blockDim.x + threadIdx.x;
    int stride = gridDim.x * blockDim.x;
    for (; i < TOTAL_UNITS; i += stride) {
        if (i < G_UNITS) {
            // ---- gather: mem_out = memory[node_idxs] (+ lu_out at col0) ----
            int row  = i >> 5;
            int col4 = i & 31;
            int idx  = node_idxs[row];
            f4 v = mem4[(long)idx * 32 + col4];      // cached: duplicate rows
            memout4[i] = v;
            if (col4 == 0) {
                lu_out[row] = last_update[idx];
            }
        } else if (i < GM_UNITS) {
            // ---- set_memory: copy-or-replace, conflict-free ----
            int j    = i - G_UNITS;
            int row  = j >> 5;
            int col4 = j & 31;
            int w = winner[row];                     // uniform across row
            f4 v;
            if (w >= 0) {
                v = val4[(long)w * 32 + col4];       // cached: scattered gather
            } else {
                v = nt_load4(&mem4[j]);              // pure stream, read-once
            }
            newmem4[j] = v;
        } else {
            // ---- messages: flag-select row copy, rows of 257 floats ----
            int j = i - GM_UNITS;
            int e  = j * 4;
            int r0 = e / 257;
            int r3 = (e + 3) / 257;
            if (r0 == r3) {
                f4 v;
                if (flag[r0]) {                      // 0xFF = keep old
                    v = nt_load4(&msg4[j]);
                } else {                             // 0 = store new
                    v = nt_load4(&src4[j]);
                }
                newmsg4[j] = v;
            } else {
                #pragma unroll
                for (int k = 0; k < 4; ++k) {
                    int r = (e + k) / 257;
                    float v = (flag[r] ? messages : nid2msg)[e + k];
                    new_messages[e + k] = v;
                }
            }
        }
    }
}

// ---------------------------------------------------------------------------
extern "C" void kernel_launch(void* const* d_in, const int* in_sizes, int n_in,
                              void* d_out, int out_size, void* d_ws, size_t ws_size,
                              hipStream_t stream) {
    const float* memory       = (const float*)d_in[0];   // [N, 128]
    const float* last_update  = (const float*)d_in[1];   // [N]
    const float* messages     = (const float*)d_in[2];   // [N, 257]
    const float* nid2msg      = (const float*)d_in[3];   // [N, 257]
    const float* values       = (const float*)d_in[4];   // [B, 128]
    const int*   node_idxs    = (const int*)d_in[5];     // [B]
    const int*   nodes        = (const int*)d_in[6];     // [B]

    float* out = (float*)d_out;
    float* mem_out      = out;
    float* lu_out       = out + (long)BATCH * MEM_D;                 // 25,600,000
    float* new_memory   = lu_out + BATCH;                            // 25,800,000
    float* new_messages = new_memory + (long)N_NODES * MEM_D;        // 89,800,000

    // Workspace: winner int[N] then flag uchar[N]; both init to 0xFF in ONE memset
    int* winner = (int*)d_ws;
    unsigned char* flag = (unsigned char*)d_ws + (size_t)N_NODES * sizeof(int);

    const int BS = 256;

    hipMemsetAsync(d_ws, 0xFF,
                   (size_t)N_NODES * sizeof(int) + (size_t)N_NODES, stream);

    scatter_idx_kernel<<<(BATCH + BS - 1) / BS, BS, 0, stream>>>(
        node_idxs, nodes, winner, flag);

    fused_kernel<<<2048, BS, 0, stream>>>(memory, last_update, messages,
                                          nid2msg, values, node_idxs,
                                          winner, flag,
                                          mem_out, lu_out, new_memory,
                                          new_messages);
}

// Round 7
// 355.161 us; speedup vs baseline: 1.0757x; 1.0757x over previous
//
#include <hip/hip_runtime.h>

// Problem constants (match reference setup_inputs)
#define N_NODES 500000
#define MEM_D   128
#define MSG_W   257          // MSG_D + 1
#define BATCH   200000

#define G_UNITS   6400000    // BATCH * 32       float4 units (mem_out gather)
#define M_UNITS   16000000   // N_NODES * 32     float4 units (new_memory)
#define S_UNITS   32125000   // (N_NODES/4)*257  float4 units (new_messages)
#define MS_UNITS  48125000   // M_UNITS + S_UNITS

typedef float f4 __attribute__((ext_vector_type(4)));

__device__ __forceinline__ f4 nt_load4(const f4* p) {
    return __builtin_nontemporal_load(p);     // read-once streams: skip L2
}
__device__ __forceinline__ void nt_store4(f4* p, f4 v) {
    __builtin_nontemporal_store(v, p);        // write-once outputs: skip L2
}

// ---------------------------------------------------------------------------
// Init: winner = -1 (int[N]), flag = 0 (uchar[N] as u32)   [r3 semantics]
__global__ void init_kernel(int* __restrict__ winner,
                            unsigned int* __restrict__ flag32) {
    int i = blockIdx.x * blockDim.x + threadIdx.x;
    int stride = gridDim.x * blockDim.x;
    for (int j = i; j < N_NODES; j += stride) winner[j] = -1;
    for (int j = i; j < N_NODES / 4; j += stride) flag32[j] = 0u;  // exact
}

// ---------------------------------------------------------------------------
// Kernel 2: scatter maps + lu_out + phase A gather (gather is independent of
// winner/flag, so the scatter's random atomics hide under the gather traffic).
__global__ void prep_gather_kernel(const float* __restrict__ memory,
                                   const float* __restrict__ last_update,
                                   const int* __restrict__ node_idxs,
                                   const int* __restrict__ nodes,
                                   int* __restrict__ winner,
                                   unsigned char* __restrict__ flag,
                                   float* __restrict__ mem_out,
                                   float* __restrict__ lu_out) {
    const f4* mem4 = reinterpret_cast<const f4*>(memory);
    f4* memout4 = reinterpret_cast<f4*>(mem_out);

    const int tid = blockIdx.x * blockDim.x + threadIdx.x;
    const int stride = gridDim.x * blockDim.x;

    // scatter + lu gather (BATCH < stride -> at most 1 iter/thread)
    for (int i = tid; i < BATCH; i += stride) {
        int idx = node_idxs[i];
        atomicMax(&winner[idx], i);            // last occurrence wins
        flag[nodes[i]] = 1;                    // idempotent, race OK
        __builtin_nontemporal_store(last_update[idx], &lu_out[i]);
    }

    // phase A: mem_out = memory[node_idxs] (row gather, cached reads)
    for (int i = tid; i < G_UNITS; i += stride) {
        int row  = i >> 5;
        int col4 = i & 31;
        int idx  = node_idxs[row];
        nt_store4(&memout4[i], mem4[(long)idx * 32 + col4]);
    }
}

// ---------------------------------------------------------------------------
// Kernel 3: phases B and C, flat grid-stride (r3 structure).
__global__ void bulk_kernel(const float* __restrict__ memory,
                            const float* __restrict__ messages,
                            const float* __restrict__ nid2msg,
                            const float* __restrict__ values,
                            const int* __restrict__ winner,
                            const unsigned char* __restrict__ flag,
                            float* __restrict__ new_memory,
                            float* __restrict__ new_messages) {
    const f4* mem4 = reinterpret_cast<const f4*>(memory);
    const f4* val4 = reinterpret_cast<const f4*>(values);
    const f4* msg4 = reinterpret_cast<const f4*>(messages);
    const f4* src4 = reinterpret_cast<const f4*>(nid2msg);
    f4* newmem4 = reinterpret_cast<f4*>(new_memory);
    f4* newmsg4 = reinterpret_cast<f4*>(new_messages);

    int i = blockIdx.x * blockDim.x + threadIdx.x;
    int stride = gridDim.x * blockDim.x;
    for (; i < MS_UNITS; i += stride) {
        if (i < M_UNITS) {
            // ---- set_memory: copy-or-replace, conflict-free ----
            int row  = i >> 5;
            int col4 = i & 31;
            int w = winner[row];                 // uniform across row
            f4 v;
            if (w >= 0) {
                v = val4[(long)w * 32 + col4];   // cached: scattered gather
            } else {
                v = nt_load4(&mem4[i]);          // pure stream, read-once
            }
            nt_store4(&newmem4[i], v);
        } else {
            // ---- messages: flag-select row copy, rows of 257 floats ----
            int j = i - M_UNITS;
            int e  = j * 4;
            int r0 = e / 257;
            int r3 = (e + 3) / 257;
            if (r0 == r3) {
                f4 v;
                if (flag[r0]) {
                    v = nt_load4(&src4[j]);
                } else {
                    v = nt_load4(&msg4[j]);
                }
                nt_store4(&newmsg4[j], v);
            } else {
                #pragma unroll
                for (int k = 0; k < 4; ++k) {
                    int r = (e + k) / 257;
                    float v = (flag[r] ? nid2msg : messages)[e + k];
                    new_messages[e + k] = v;
                }
            }
        }
    }
}

// ---------------------------------------------------------------------------
extern "C" void kernel_launch(void* const* d_in, const int* in_sizes, int n_in,
                              void* d_out, int out_size, void* d_ws, size_t ws_size,
                              hipStream_t stream) {
    const float* memory       = (const float*)d_in[0];   // [N, 128]
    const float* last_update  = (const float*)d_in[1];   // [N]
    const float* messages     = (const float*)d_in[2];   // [N, 257]
    const float* nid2msg      = (const float*)d_in[3];   // [N, 257]
    const float* values       = (const float*)d_in[4];   // [B, 128]
    const int*   node_idxs    = (const int*)d_in[5];     // [B]
    const int*   nodes        = (const int*)d_in[6];     // [B]

    float* out = (float*)d_out;
    float* mem_out      = out;
    float* lu_out       = out + (long)BATCH * MEM_D;                 // 25,600,000
    float* new_memory   = lu_out + BATCH;                            // 25,800,000
    float* new_messages = new_memory + (long)N_NODES * MEM_D;        // 89,800,000

    // Workspace: winner map (int[N]) + touched flag (uchar[N]) = 2.5 MB
    int* winner = (int*)d_ws;
    unsigned char* flag = (unsigned char*)d_ws + (size_t)N_NODES * sizeof(int);

    const int BS = 256;

    init_kernel<<<512, BS, 0, stream>>>(winner, (unsigned int*)flag);

    prep_gather_kernel<<<2048, BS, 0, stream>>>(memory, last_update,
                                                node_idxs, nodes,
                                                winner, flag,
                                                mem_out, lu_out);

    bulk_kernel<<<2048, BS, 0, stream>>>(memory, messages, nid2msg, values,
                                         winner, flag,
                                         new_memory, new_messages);
}